// Round 8
// baseline (161.092 us; speedup 1.0000x reference)
//
#include <hip/hip_runtime.h>
#include <math.h>

// Problem constants
#define E_     64     // embedding dim == wavefront size
#define ND_    40     // diseases per visit
#define NM_    30     // medications per visit
#define NSTEP_ 31     // NM+1 decode steps
#define VO_    133    // VM+2 output vocab
#define J3_    192    // 3*E (GRU gates)
#define NROW_  8192   // B*S
#define SOS_   131    // VM
#define NCW_   196    // per-wave sC stride (floats)
#define NWOT_  9      // wo n-tiles (144 cols cover 133)

typedef __attribute__((ext_vector_type(8))) short short8;
typedef __attribute__((ext_vector_type(4))) float f32x4;

__device__ __forceinline__ float sigmoidf_(float x){ return 1.f/(1.f+__expf(-x)); }
__device__ __forceinline__ float tanhf_(float x){
  float ax = fabsf(x);
  float t = 1.f - 2.f/(__expf(2.f*ax)+1.f);   // stable, saturates to 1
  return copysignf(t, x);
}
__device__ __forceinline__ unsigned short f2bf(float f){
  union { float f; unsigned u; } x; x.f = f;
  unsigned r = (x.u + 0x7fffu + ((x.u >> 16) & 1u)) >> 16;  // RNE
  return (unsigned short)r;
}
__device__ __forceinline__ short8 pack8_(const float* __restrict__ s){
  short8 f;
  #pragma unroll
  for (int j=0;j<8;++j) f[j] = (short)f2bf(s[j]);
  return f;
}

// ---------------------------------------------------------------------------
// Kernel A: P_med[v][j] = sum_e med_table[v][e] * W_ih[j][64+e]   (134x192)
// ---------------------------------------------------------------------------
__global__ __launch_bounds__(256) void k_pmed(const float* __restrict__ mt,
    const float* __restrict__ wih, float* __restrict__ pmed){
  int o = blockIdx.x*256 + threadIdx.x;
  if (o >= 134*J3_) return;
  int v = o / J3_, j = o - v*J3_;
  const float* mr = mt + v*E_;
  const float* wr = wih + j*128 + E_;
  float a = 0.f;
  #pragma unroll
  for (int k=0;k<E_;k++) a = fmaf(mr[k], wr[k], a);
  pmed[o] = a;
}

// ---------------------------------------------------------------------------
// Fused barrier-free decoder. One wave owns 4 rows end-to-end (wave-private
// LDS; DS in-order per wave; NO s_barrier in the loop). Per step:
//   A(h_t) -> gh GEMM (12 Whh reg-frag tiles) -> LDS redistribute ->
//   pointwise GRU -> h_{t+1} -> A re-read -> logits GEMM (9 wo tiles, B
//   staged bf16+XOR-swizzled in LDS) -> in-register max-free log_softmax
//   (16 l4==0 lanes: 9 exp-sums + 4-deep l15 butterfly) -> stores (never
//   drained). The logits/softmax/store block is OFF the recurrence critical
//   path (next A-read depends only on the h-write) -> rides in the latency
//   bubbles (round-2 evidence: fused == recurrence-only wall time).
// 512 blocks x 256 thr; launch_bounds(256,2): VGPR cap 256, live ~215.
// ---------------------------------------------------------------------------
__global__ __launch_bounds__(256,2) void k_fused(
    const int* __restrict__ dis, const float* __restrict__ dmask,
    const float* __restrict__ dt, const float* __restrict__ aw,
    const int* __restrict__ meds,
    const float* __restrict__ whh, const float* __restrict__ bhh,
    const float* __restrict__ wih, const float* __restrict__ bih,
    const float* __restrict__ wo, const float* __restrict__ wob,
    const float* __restrict__ mt, const float* __restrict__ pmed,
    float* __restrict__ out)
{
  __shared__ unsigned short sWo[NWOT_*16*E_];             // 18KB swz bf16 wo
  __shared__ __align__(16) unsigned short hAall[4][4*80]; // 640B/wave bf16 h
  __shared__ __align__(16) float sCall[4][4*NCW_];        // 3.1KB/wave C out
  __shared__ int sLMall[4][128];                          // last-med idx

  const int tid = threadIdx.x;
  const int w = tid >> 6, l = tid & 63;
  const int l15 = l & 15, l4 = l >> 4;
  const int ral = l15 & 3;                 // A-row broadcast source
  const int rbase = blockIdx.x*16 + w*4;   // this wave's 4 rows
  unsigned short* myA = hAall[w];
  float*          myC = sCall[w];
  int*            myL = sLMall[w];

  // ---- stage wo^T as bf16 with 16B-chunk XOR swizzle (block-wide) ----
  for (int idx = tid; idx < NWOT_*16*E_; idx += 256){
    int c = idx >> 6, k = idx & 63;
    float v = (c < VO_) ? wo[(size_t)c*E_ + k] : 0.f;
    sWo[c*E_ + (((k>>3) ^ (c&7))<<3) + (k&7)] = f2bf(v);
  }

  // ---- last-med indices for 4 rows x 31 steps (wave-private) ----
  #pragma unroll
  for (int i = l; i < 128; i += 64){
    int rr = i >> 5, t = i & 31;
    if (t < NSTEP_)
      myL[i] = (t==0) ? SOS_ : meds[(size_t)(rbase+rr)*NM_ + (t-1)];
  }

  // ======== prologue: attention ctx for the 4 rows (h-independent) ========
  float wd = aw[E_ + l];
  #pragma unroll 1
  for (int r = 0; r < 4; ++r){
    const int*   drow = dis   + (size_t)(rbase+r)*ND_;
    const float* mrow = dmask + (size_t)(rbase+r)*ND_;
    float dreg[ND_], sc[ND_];
    float mx = -INFINITY;
    #pragma unroll
    for (int n = 0; n < ND_; ++n){
      float d = dt[(size_t)drow[n]*E_ + l];
      dreg[n] = d;
      float p = d * wd;
      #pragma unroll
      for (int m=1;m<64;m<<=1) p += __shfl_xor(p, m);
      sc[n] = p + mrow[n];
      mx = fmaxf(mx, sc[n]);
    }
    float ss = 0.f, ctx = 0.f;
    #pragma unroll
    for (int n = 0; n < ND_; ++n){
      float e = __expf(sc[n]-mx);
      ss += e;
      ctx = fmaf(e, dreg[n], ctx);
    }
    ctx /= ss;
    myA[r*80 + l] = f2bf(ctx);
  }

  // ======== prologue: gi = ctx @ W_ih_left^T (wave-private MFMA) ========
  {
    short8 A00 = *(const short8*)&myA[ral*80 + l4*8];
    short8 A01 = *(const short8*)&myA[ral*80 + l4*8 + 32];
    #pragma unroll 1
    for (int j = 0; j < 12; ++j){
      int c = j*16 + l15;
      short8 B0 = pack8_(wih + (size_t)c*128 + l4*8);
      short8 B1 = pack8_(wih + (size_t)c*128 + 32 + l4*8);
      f32x4 cc = {0.f,0.f,0.f,0.f};
      cc = __builtin_amdgcn_mfma_f32_16x16x32_bf16(A00, B0, cc, 0,0,0);
      cc = __builtin_amdgcn_mfma_f32_16x16x32_bf16(A01, B1, cc, 0,0,0);
      if (l4 == 0){
        #pragma unroll
        for (int i=0;i<4;i++) myC[i*NCW_ + c] = cc[i];
      }
    }
  }
  // redistribute: lane -> row l4, dims 4*l15 + {0,64,128}; fold biases
  f32x4 gi_r = *(const f32x4*)&myC[l4*NCW_ + 4*l15];
  f32x4 gi_z = *(const f32x4*)&myC[l4*NCW_ + 4*l15 + 64];
  f32x4 gi_n = *(const f32x4*)&myC[l4*NCW_ + 4*l15 + 128];
  {
    f32x4 bihr = *(const f32x4*)&bih[4*l15];
    f32x4 bihz = *(const f32x4*)&bih[4*l15 + 64];
    f32x4 bihn = *(const f32x4*)&bih[4*l15 + 128];
    f32x4 bhhr = *(const f32x4*)&bhh[4*l15];
    f32x4 bhhz = *(const f32x4*)&bhh[4*l15 + 64];
    #pragma unroll
    for (int i=0;i<4;++i){
      gi_r[i] += bihr[i] + bhhr[i];
      gi_z[i] += bihz[i] + bhhz[i];
      gi_n[i] += bihn[i];
    }
  }
  f32x4 bhn = *(const f32x4*)&bhh[4*l15 + 128];

  // ======== loop-invariant W_hh^T B-fragments (12 tiles, 96 VGPR) ========
  short8 WB0[12], WB1[12];
  #pragma unroll
  for (int j = 0; j < 12; ++j){
    int c = j*16 + l15;
    WB0[j] = pack8_(whh + (size_t)c*E_ + l4*8);
    WB1[j] = pack8_(whh + (size_t)c*E_ + 32 + l4*8);
  }

  // wob per logits tile (col c_wo = jl*16 + l15); invalid -> -1e30 (exp->0)
  float wbv[NWOT_];
  #pragma unroll
  for (int jl = 0; jl < NWOT_; ++jl){
    int cw = jl*16 + l15;
    wbv[jl] = (cw < VO_) ? wob[cw] : -1e30f;
  }

  // ======== h0 = med_table[SOS]; lane holds row l4, dims 4*l15..+3 ========
  f32x4 hrv = *(const f32x4*)&mt[SOS_*E_ + 4*l15];
  {
    uint2 hv;
    hv.x = (unsigned)f2bf(hrv[0]) | ((unsigned)f2bf(hrv[1])<<16);
    hv.y = (unsigned)f2bf(hrv[2]) | ((unsigned)f2bf(hrv[3])<<16);
    *(uint2*)&myA[l4*80 + 4*l15] = hv;
  }

  __syncthreads();   // sWo staged (only cross-wave dependency; loop is bar-free)

  // ---- prefetch pmed for t=0 ----
  int lm0 = myL[l4*32];
  f32x4 p_r = *(const f32x4*)&pmed[(size_t)lm0*J3_ + 4*l15];
  f32x4 p_z = *(const f32x4*)&pmed[(size_t)lm0*J3_ + 4*l15 + 64];
  f32x4 p_n = *(const f32x4*)&pmed[(size_t)lm0*J3_ + 4*l15 + 128];

  // ======== main loop: 31 steps, zero barriers ========
  for (int t = 0; t < NSTEP_; ++t){
    // ---- gh GEMM from h_t ----
    short8 A00 = *(const short8*)&myA[ral*80 + l4*8];
    short8 A01 = *(const short8*)&myA[ral*80 + l4*8 + 32];
    int lmn = (t+1 < NSTEP_) ? myL[l4*32 + t + 1] : 0;
    #pragma unroll
    for (int j = 0; j < 12; ++j){
      f32x4 cc = {0.f,0.f,0.f,0.f};
      cc = __builtin_amdgcn_mfma_f32_16x16x32_bf16(A00, WB0[j], cc, 0,0,0);
      cc = __builtin_amdgcn_mfma_f32_16x16x32_bf16(A01, WB1[j], cc, 0,0,0);
      if (l4 == 0){
        int c = j*16 + l15;
        myC[0*NCW_ + c] = cc[0];
        myC[1*NCW_ + c] = cc[1];
        myC[2*NCW_ + c] = cc[2];
        myC[3*NCW_ + c] = cc[3];
      }
    }
    // redistribute gh (wave-private LDS, in-order DS)
    f32x4 ghr = *(const f32x4*)&myC[l4*NCW_ + 4*l15];
    f32x4 ghz = *(const f32x4*)&myC[l4*NCW_ + 4*l15 + 64];
    f32x4 ghn = *(const f32x4*)&myC[l4*NCW_ + 4*l15 + 128];
    // ---- pointwise GRU (4 dims of row rbase+l4) ----
    #pragma unroll
    for (int i=0;i<4;++i){
      float ir  = gi_r[i] + p_r[i] + ghr[i];
      float iz  = gi_z[i] + p_z[i] + ghz[i];
      float in2 = gi_n[i] + p_n[i];
      float hn  = ghn[i] + bhn[i];
      float rg = sigmoidf_(ir), zg = sigmoidf_(iz);
      float ng = tanhf_(in2 + rg*hn);
      hrv[i] = (1.f - zg)*ng + zg*hrv[i];
    }
    {
      uint2 hv;
      hv.x = (unsigned)f2bf(hrv[0]) | ((unsigned)f2bf(hrv[1])<<16);
      hv.y = (unsigned)f2bf(hrv[2]) | ((unsigned)f2bf(hrv[3])<<16);
      *(uint2*)&myA[l4*80 + 4*l15] = hv;      // h_{t+1}
    }
    if (t+1 < NSTEP_){                        // prefetch pmed for t+1
      p_r = *(const f32x4*)&pmed[(size_t)lmn*J3_ + 4*l15];
      p_z = *(const f32x4*)&pmed[(size_t)lmn*J3_ + 4*l15 + 64];
      p_n = *(const f32x4*)&pmed[(size_t)lmn*J3_ + 4*l15 + 128];
    }

    // ---- logits from h_{t+1} (off the recurrence critical path) ----
    short8 An0 = *(const short8*)&myA[ral*80 + l4*8];
    short8 An1 = *(const short8*)&myA[ral*80 + l4*8 + 32];
    f32x4 vcl[NWOT_];
    #pragma unroll
    for (int jl = 0; jl < NWOT_; ++jl){
      int cw = jl*16 + l15;
      short8 B0 = *(const short8*)&sWo[cw*E_ + (((l4  ) ^ (cw&7))<<3)];
      short8 B1 = *(const short8*)&sWo[cw*E_ + (((l4+4) ^ (cw&7))<<3)];
      f32x4 cc = {0.f,0.f,0.f,0.f};
      cc = __builtin_amdgcn_mfma_f32_16x16x32_bf16(An0, B0, cc, 0,0,0);
      cc = __builtin_amdgcn_mfma_f32_16x16x32_bf16(An1, B1, cc, 0,0,0);
      #pragma unroll
      for (int i=0;i<4;++i) vcl[jl][i] = cc[i] + wbv[jl];
    }
    // max-free log_softmax in C-layout: rows i in lanes l4==0 (cols l15)
    float s0=0.f, s1=0.f, s2=0.f, s3=0.f;
    #pragma unroll
    for (int jl = 0; jl < NWOT_; ++jl){
      s0 += __expf(vcl[jl][0]);
      s1 += __expf(vcl[jl][1]);
      s2 += __expf(vcl[jl][2]);
      s3 += __expf(vcl[jl][3]);
    }
    #pragma unroll
    for (int mm=1; mm<16; mm<<=1){            // butterfly over l15 (16 lanes)
      s0 += __shfl_xor(s0, mm);
      s1 += __shfl_xor(s1, mm);
      s2 += __shfl_xor(s2, mm);
      s3 += __shfl_xor(s3, mm);
    }
    float lg0 = __logf(s0), lg1 = __logf(s1), lg2 = __logf(s2), lg3 = __logf(s3);
    if (l4 == 0){
      #pragma unroll
      for (int jl = 0; jl < NWOT_; ++jl){
        int cw = jl*16 + l15;
        if (cw < VO_){
          out[((size_t)(rbase+0)*NSTEP_ + t)*VO_ + cw] = vcl[jl][0] - lg0;
          out[((size_t)(rbase+1)*NSTEP_ + t)*VO_ + cw] = vcl[jl][1] - lg1;
          out[((size_t)(rbase+2)*NSTEP_ + t)*VO_ + cw] = vcl[jl][2] - lg2;
          out[((size_t)(rbase+3)*NSTEP_ + t)*VO_ + cw] = vcl[jl][3] - lg3;
        }
      }
    }
  }
}

extern "C" void kernel_launch(void* const* d_in, const int* in_sizes, int n_in,
                              void* d_out, int out_size, void* d_ws, size_t ws_size,
                              hipStream_t stream){
  const int*   dis  = (const int*)  d_in[0];
  const int*   meds = (const int*)  d_in[2];
  const float* dmask= (const float*)d_in[3];
  const float* dt   = (const float*)d_in[6];
  const float* mt   = (const float*)d_in[7];
  const float* aw   = (const float*)d_in[8];
  const float* wih  = (const float*)d_in[10];
  const float* whh  = (const float*)d_in[11];
  const float* bih  = (const float*)d_in[12];
  const float* bhh  = (const float*)d_in[13];
  const float* wo   = (const float*)d_in[14];
  const float* wob  = (const float*)d_in[15];
  float* outp = (float*)d_out;
  float* pmed = (float*)d_ws;                               // 134*192 f32

  k_pmed <<<(134*J3_+255)/256, 256, 0, stream>>>(mt, wih, pmed);
  k_fused<<<NROW_/16,          256, 0, stream>>>(dis, dmask, dt, aw, meds,
                                                 whh, bhh, wih, bih, wo, wob,
                                                 mt, pmed, outp);
}

// Round 10
// 97.918 us; speedup vs baseline: 1.6452x; 1.6452x over previous
//
#include <hip/hip_runtime.h>
#include <math.h>

// Problem constants
#define E_     64     // embedding dim == wavefront size
#define ND_    40     // diseases per visit
#define NM_    30     // medications per visit
#define NSTEP_ 31     // NM+1 decode steps
#define VO_    133    // VM+2 output vocab
#define J3_    192    // 3*E (GRU gates)
#define NROW_  8192   // B*S
#define RPB_   16     // rows per block (= M-tile, all real)
#define SOS_   131    // VM
#define NC_    344    // sC stride (f32): 336 used cols + pad
#define NACT_  325    // combined cols: 192 gh + 133 logits

typedef __attribute__((ext_vector_type(8))) short short8;
typedef __attribute__((ext_vector_type(4))) float f32x4;

__device__ __forceinline__ float sigmoidf_(float x){ return 1.f/(1.f+__expf(-x)); }
__device__ __forceinline__ float tanhf_(float x){
  float ax = fabsf(x);
  float t = 1.f - 2.f/(__expf(2.f*ax)+1.f);   // stable, saturates to 1
  return copysignf(t, x);
}
__device__ __forceinline__ unsigned short f2bf(float f){
  union { float f; unsigned u; } x; x.f = f;
  unsigned r = (x.u + 0x7fffu + ((x.u >> 16) & 1u)) >> 16;  // RNE
  return (unsigned short)r;
}
__device__ __forceinline__ short8 pack8_(const float* __restrict__ s){
  short8 f;
  #pragma unroll
  for (int j=0;j<8;++j) f[j] = (short)f2bf(s[j]);
  return f;
}

// lgkm-only barrier: does NOT drain vmcnt, so in-flight global stores
// (output stream) are never waited on at step boundaries.
__device__ __forceinline__ void bar_lds(){
  asm volatile("s_waitcnt lgkmcnt(0)" ::: "memory");
  __builtin_amdgcn_s_barrier();
  asm volatile("" ::: "memory");
}

// ---------------------------------------------------------------------------
// Kernel A: P_med[v][j] = sum_e med_table[v][e] * W_ih[j][64+e]   (134x192)
// ---------------------------------------------------------------------------
__global__ __launch_bounds__(256) void k_pmed(const float* __restrict__ mt,
    const float* __restrict__ wih, float* __restrict__ pmed){
  int o = blockIdx.x*256 + threadIdx.x;
  if (o >= 134*J3_) return;
  int v = o / J3_, j = o - v*J3_;
  const float* mr = mt + v*E_;
  const float* wr = wih + j*128 + E_;
  float a = 0.f;
  #pragma unroll
  for (int k=0;k<E_;k++) a = fmaf(mr[k], wr[k], a);
  pmed[o] = a;
}

// ---------------------------------------------------------------------------
// Fused cooperative decoder (round-4 structure, spill-free, store-decoupled).
// 512 blocks x 512 threads (8 waves), 16 rows/block = full M-tile (no waste),
// 2 blocks/CU resident (16 waves/CU, whole grid co-resident).
// Per step: combined GEMM h_t(16x64) x [W_hh^T|wo^T](64x336) — 21 n-tiles
// split {w, w+8, w+16(w<5)} across 8 waves, B as register fragments
// (<=24 VGPR/wave); pointwise GRU 2 dims/thread; logits(t-1) softmax 32-wide.
// bar_lds only; pmed loads for t+1 issued BEFORE step-t out stores so the
// vmcnt in-order retire never waits on the output stream.
// ---------------------------------------------------------------------------
__global__ __launch_bounds__(512,4) void k_main(
    const int* __restrict__ dis, const float* __restrict__ dmask,
    const float* __restrict__ dt, const float* __restrict__ aw,
    const int* __restrict__ meds,
    const float* __restrict__ whh, const float* __restrict__ bhh,
    const float* __restrict__ wih, const float* __restrict__ bih,
    const float* __restrict__ wo, const float* __restrict__ wob,
    const float* __restrict__ mt, const float* __restrict__ pmed,
    float* __restrict__ out)
{
  __shared__ __align__(16) unsigned short hA[RPB_*E_];  // 2KB swizzled bf16 h
  __shared__ __align__(16) float sC[RPB_*NC_];          // 22KB GEMM out
  __shared__ int sLM[RPB_*32];                          // 2KB last-med idx

  const int tid = threadIdx.x;
  const int w = tid >> 6, l = tid & 63;
  const int l15 = l & 15, l4 = l >> 4;
  const int row = tid >> 5;                 // pointwise row (0..15)
  const int d0  = (tid & 31) * 2;           // pointwise dim pair
  const int rowbase = blockIdx.x * RPB_;
  const int grow = rowbase + row;

  // ---- last-med indices ----
  {
    int rr = tid >> 5, t = tid & 31;
    if (t < NSTEP_)
      sLM[rr*32 + t] = (t==0) ? SOS_ : meds[(size_t)(rowbase+rr)*NM_ + (t-1)];
  }

  // ======== prologue: attention ctx for rows 2w, 2w+1 (h-independent) ====
  float wd = aw[E_ + l];
  #pragma unroll 1
  for (int r2 = 0; r2 < 2; ++r2){
    int rr = 2*w + r2;
    const int*   drow = dis   + (size_t)(rowbase+rr)*ND_;
    const float* mrow = dmask + (size_t)(rowbase+rr)*ND_;
    float dreg[ND_], sc[ND_];
    float mx = -INFINITY;
    #pragma unroll
    for (int n = 0; n < ND_; ++n){
      float d = dt[(size_t)drow[n]*E_ + l];
      dreg[n] = d;
      float p = d * wd;
      #pragma unroll
      for (int m=1;m<64;m<<=1) p += __shfl_xor(p, m);
      sc[n] = p + mrow[n];
      mx = fmaxf(mx, sc[n]);
    }
    float ss = 0.f, ctx = 0.f;
    #pragma unroll
    for (int n = 0; n < ND_; ++n){
      float e = __expf(sc[n]-mx);
      ss += e;
      ctx = fmaf(e, dreg[n], ctx);
    }
    ctx /= ss;
    hA[rr*E_ + (l ^ ((rr&7)<<3))] = f2bf(ctx);   // swizzled A-tile row
  }
  __syncthreads();

  // ======== prologue: gi = ctx @ W_ih_left^T (cooperative MFMA) ========
  {
    short8 A00 = *(const short8*)&hA[l15*E_ + ((l4*8     ) ^ ((l15&7)<<3))];
    short8 A01 = *(const short8*)&hA[l15*E_ + ((32 + l4*8) ^ ((l15&7)<<3))];
    #pragma unroll
    for (int jj = 0; jj < 2; ++jj){
      int n = w + 8*jj;
      if (n < 12){                              // 12 tiles cover 192 cols
        int c = n*16 + l15;
        short8 B0 = pack8_(wih + (size_t)c*128 + l4*8);
        short8 B1 = pack8_(wih + (size_t)c*128 + 32 + l4*8);
        f32x4 cc = {0.f,0.f,0.f,0.f};
        cc = __builtin_amdgcn_mfma_f32_16x16x32_bf16(A00, B0, cc, 0,0,0);
        cc = __builtin_amdgcn_mfma_f32_16x16x32_bf16(A01, B1, cc, 0,0,0);
        #pragma unroll
        for (int i=0;i<4;i++) sC[(l4*4+i)*NC_ + c] = cc[i];
      }
    }
  }
  __syncthreads();
  // per-thread gi (row, dims d0..d0+1), fold biases
  float2 gir = *(const float2*)&sC[row*NC_ + d0];
  float2 giz = *(const float2*)&sC[row*NC_ + d0 + 64];
  float2 gin = *(const float2*)&sC[row*NC_ + d0 + 128];
  {
    float2 a = *(const float2*)&bih[d0],      b = *(const float2*)&bhh[d0];
    float2 c = *(const float2*)&bih[d0+64],   d = *(const float2*)&bhh[d0+64];
    float2 e = *(const float2*)&bih[d0+128];
    gir.x += a.x + b.x; gir.y += a.y + b.y;
    giz.x += c.x + d.x; giz.y += c.y + d.y;
    gin.x += e.x;       gin.y += e.y;
  }
  float2 bhn = *(const float2*)&bhh[d0 + 128];
  // wob per softmax col (idx = (tid&31) + 32k)
  float wbv[5];
  #pragma unroll
  for (int k = 0; k < 5; ++k){
    int idx = (tid&31) + 32*k;
    wbv[k] = (idx < VO_) ? wob[idx] : -1e30f;
  }

  // ======== combined-weight register B-fragments: wave w tiles {w,w+8,w+16}
  short8 B0[3], B1[3];
  const int ntile = (w < 5) ? 3 : 2;
  #pragma unroll
  for (int j = 0; j < 3; ++j){
    short8 z = {0,0,0,0,0,0,0,0};
    B0[j] = z; B1[j] = z;
    if (j < ntile){
      int c = (w + 8*j)*16 + l15;
      #pragma unroll
      for (int ks = 0; ks < 2; ++ks){
        int k0 = ks*32 + l4*8;
        float v[8];
        if (c < J3_){
          const float* s = whh + (size_t)c*E_ + k0;
          #pragma unroll
          for (int jj=0;jj<8;jj++) v[jj] = s[jj];
        } else if (c < 192+VO_){
          const float* s = wo + (size_t)(c-192)*E_ + k0;
          #pragma unroll
          for (int jj=0;jj<8;jj++) v[jj] = s[jj];
        } else {
          #pragma unroll
          for (int jj=0;jj<8;jj++) v[jj] = 0.f;
        }
        short8 f;
        #pragma unroll
        for (int jj=0;jj<8;jj++) f[jj] = (short)f2bf(v[jj]);
        if (ks==0) B0[j] = f; else B1[j] = f;
      }
    }
  }

  // ======== h0 = med_table[SOS]; thread holds (row, dims d0..d0+1) ========
  float2 hv2 = *(const float2*)&mt[SOS_*E_ + d0];
  {
    unsigned hv = (unsigned)f2bf(hv2.x) | ((unsigned)f2bf(hv2.y)<<16);
    *(unsigned*)&hA[row*E_ + (d0 ^ ((row&7)<<3))] = hv;
  }
  __syncthreads();

  // ---- prefetch pmed for t=0 ----
  int lm = sLM[row*32];
  float2 pr = *(const float2*)&pmed[(size_t)lm*J3_ + d0];
  float2 pz = *(const float2*)&pmed[(size_t)lm*J3_ + d0 + 64];
  float2 pn = *(const float2*)&pmed[(size_t)lm*J3_ + d0 + 128];

  // ======== main loop: 32 iterations (gh at t, logits for t-1) ========
  for (int t = 0; t <= NSTEP_; ++t){
    short8 A00 = *(const short8*)&hA[l15*E_ + ((l4*8     ) ^ ((l15&7)<<3))];
    short8 A01 = *(const short8*)&hA[l15*E_ + ((32 + l4*8) ^ ((l15&7)<<3))];
    #pragma unroll
    for (int j = 0; j < 3; ++j){
      if (j < ntile){
        f32x4 cc = {0.f,0.f,0.f,0.f};
        cc = __builtin_amdgcn_mfma_f32_16x16x32_bf16(A00, B0[j], cc, 0,0,0);
        cc = __builtin_amdgcn_mfma_f32_16x16x32_bf16(A01, B1[j], cc, 0,0,0);
        int c = (w + 8*j)*16 + l15;
        #pragma unroll
        for (int i=0;i<4;i++) sC[(l4*4+i)*NC_ + c] = cc[i];
      }
    }
    bar_lds();

    // ---- prefetch pmed for t+1 (LOADS issued BEFORE this step's stores) --
    int lmn = 0; float2 npr, npz, npn;
    if (t+1 < NSTEP_){
      lmn = sLM[row*32 + t + 1];
      npr = *(const float2*)&pmed[(size_t)lmn*J3_ + d0];
      npz = *(const float2*)&pmed[(size_t)lmn*J3_ + d0 + 64];
      npn = *(const float2*)&pmed[(size_t)lmn*J3_ + d0 + 128];
    }

    if (t < NSTEP_){
      // ---- pointwise GRU: 2 dims of row `row` ----
      float2 ghr = *(const float2*)&sC[row*NC_ + d0];
      float2 ghz = *(const float2*)&sC[row*NC_ + d0 + 64];
      float2 ghn = *(const float2*)&sC[row*NC_ + d0 + 128];
      {
        float rg = sigmoidf_(gir.x + pr.x + ghr.x);
        float zg = sigmoidf_(giz.x + pz.x + ghz.x);
        float ng = tanhf_(gin.x + pn.x + rg*(ghn.x + bhn.x));
        hv2.x = (1.f - zg)*ng + zg*hv2.x;
      }
      {
        float rg = sigmoidf_(gir.y + pr.y + ghr.y);
        float zg = sigmoidf_(giz.y + pz.y + ghz.y);
        float ng = tanhf_(gin.y + pn.y + rg*(ghn.y + bhn.y));
        hv2.y = (1.f - zg)*ng + zg*hv2.y;
      }
      unsigned hv = (unsigned)f2bf(hv2.x) | ((unsigned)f2bf(hv2.y)<<16);
      *(unsigned*)&hA[row*E_ + (d0 ^ ((row&7)<<3))] = hv;
    }

    if (t >= 1){
      // ---- max-free log_softmax for step t-1 (logits = sC cols 192..324) -
      float lv[5]; float s = 0.f;
      #pragma unroll
      for (int k = 0; k < 5; ++k){
        int idx = (tid&31) + 32*k;
        lv[k] = (idx < VO_) ? (sC[row*NC_ + 192 + idx] + wbv[k]) : -1e30f;
        s += __expf(lv[k]);
      }
      #pragma unroll
      for (int mm=1; mm<32; mm<<=1) s += __shfl_xor(s, mm);  // 32-wide (row)
      float lg = __logf(s);
      size_t ob = ((size_t)grow*NSTEP_ + (t-1))*VO_;
      #pragma unroll
      for (int k = 0; k < 5; ++k){
        int idx = (tid&31) + 32*k;
        if (idx < VO_) out[ob + idx] = lv[k] - lg;
      }
    }
    bar_lds();

    if (t+1 < NSTEP_){ pr = npr; pz = npz; pn = npn; }
  }
}

extern "C" void kernel_launch(void* const* d_in, const int* in_sizes, int n_in,
                              void* d_out, int out_size, void* d_ws, size_t ws_size,
                              hipStream_t stream){
  const int*   dis  = (const int*)  d_in[0];
  const int*   meds = (const int*)  d_in[2];
  const float* dmask= (const float*)d_in[3];
  const float* dt   = (const float*)d_in[6];
  const float* mt   = (const float*)d_in[7];
  const float* aw   = (const float*)d_in[8];
  const float* wih  = (const float*)d_in[10];
  const float* whh  = (const float*)d_in[11];
  const float* bih  = (const float*)d_in[12];
  const float* bhh  = (const float*)d_in[13];
  const float* wo   = (const float*)d_in[14];
  const float* wob  = (const float*)d_in[15];
  float* outp = (float*)d_out;
  float* pmed = (float*)d_ws;                     // 134*192 f32

  k_pmed<<<(134*J3_+255)/256, 256, 0, stream>>>(mt, wih, pmed);
  k_main<<<NROW_/RPB_, 512, 0, stream>>>(dis, dmask, dt, aw, meds,
                                         whh, bhh, wih, bih, wo, wob,
                                         mt, pmed, outp);
}